// Round 11
// baseline (219.414 us; speedup 1.0000x reference)
//
#include <hip/hip_runtime.h>

namespace {
constexpr int NB = 32;      // batch
constexpr int NN = 2000;    // nodes
constexpr int NE = 64000;   // edges
constexpr int ND = 128;     // feature dim
constexpr int TR = 32;      // tile rows
constexpr int NCHUNK = (NN + TR - 1) / TR;   // 63
constexpr int NXCD = 8;
constexpr int BPB = 2;                        // batches per block
constexpr int PAIRS = NB / (NXCD * BPB);      // 2
constexpr int GRID_FUSED = NXCD * PAIRS * NCHUNK;  // 1008
constexpr int SL = 80;      // slot stride per node (Poisson(32); P(deg>80)~1e-12)
constexpr int ECAP = 1536;  // staged in-edge cap per 32-row tile (mean 1024)

constexpr int CVT_BLOCKS  = 8000;  // 8000*256 float4 = 8.192M floats exactly
constexpr int NODE_BLOCKS = 250;   // each owns 8 nodes; atomic-free graph build
constexpr int W_BLOCKS    = 8;     // W1 prepack + y/done zero
constexpr int PREP_GRID   = CVT_BLOCKS + NODE_BLOCKS + W_BLOCKS;

// ---- workspace layout (bytes); everything written each launch before read ----
constexpr size_t OFF_CNT  = 0;                 // int[2048]  in-degree (exclusive writes)
constexpr size_t OFF_OCNT = 8192;              // int[2048]  out-degree
constexpr size_t OFF_Y    = 16384;             // float[4096] (zeroed by W blocks)
constexpr size_t OFF_DONE = 32768;             // int
constexpr size_t OFF_SLI  = 32832;             // int[NN*SL] in-edge srcs  (640 KB)
constexpr size_t OFF_SLO  = OFF_SLI + (size_t)NN * SL * 4;   // int[NN*SL] out-edge dsts
constexpr size_t OFF_WF   = OFF_SLO + (size_t)NN * SL * 4;   // bf16 W1 frags (32 KB)
constexpr size_t OFF_XBF  = OFF_WF + 32768;    // ushort[NB*NN*ND] = 16.384 MB

typedef __attribute__((ext_vector_type(8))) short bf16x8;
typedef __attribute__((ext_vector_type(4))) float f32x4;

// f32 -> bf16 (round-to-nearest-even), bit arithmetic; inputs finite
__device__ __forceinline__ ushort f32_to_bf16(float f) {
    uint u = __float_as_uint(f);
    u += 0x7fffu + ((u >> 16) & 1u);
    return (ushort)(u >> 16);
}
__device__ __forceinline__ uint pack_bf16x2(float lo, float hi) {
    return (uint)f32_to_bf16(lo) | ((uint)f32_to_bf16(hi) << 16);
}
} // namespace

// ---- N1: heterogeneous prep: cvt X | node-owner graph build | W prepack + zero ----
__global__ void k_prep(const float* __restrict__ X, ushort* __restrict__ xbf,
                       const float* __restrict__ W1, uint* __restrict__ wf,
                       const int* __restrict__ src, const int* __restrict__ dst,
                       int* __restrict__ cnt, int* __restrict__ ocnt,
                       int* __restrict__ slot_in, int* __restrict__ slot_out,
                       float* __restrict__ y, int* __restrict__ done) {
    const int blk = blockIdx.x;
    const int tid = threadIdx.x;
    if (blk < CVT_BLOCKS) {
        int i = blk * 256 + tid;              // float4 index, exact bounds
        float4 v = ((const float4*)X)[i];
        ushort4 o;
        o.x = f32_to_bf16(v.x);
        o.y = f32_to_bf16(v.y);
        o.z = f32_to_bf16(v.z);
        o.w = f32_to_bf16(v.w);
        ((ushort4*)xbf)[i] = o;
    } else if (blk < CVT_BLOCKS + NODE_BLOCKS) {
        // owns nodes [base, base+8); scans all edges; LDS cursors; NO global atomics
        const int base = (blk - CVT_BLOCKS) * 8;
        __shared__ int lcin[8], lcout[8];
        if (tid < 8) { lcin[tid] = 0; lcout[tid] = 0; }
        __syncthreads();
        const int4* s4p = (const int4*)src;
        const int4* d4p = (const int4*)dst;
        for (int i = tid; i < NE / 4; i += 256) {
            int4 s4 = s4p[i], d4 = d4p[i];
            int ss[4] = {s4.x, s4.y, s4.z, s4.w};
            int dd[4] = {d4.x, d4.y, d4.z, d4.w};
            #pragma unroll
            for (int q = 0; q < 4; q++) {
                int j = dd[q] - base;
                if ((unsigned)j < 8u) {
                    int p = atomicAdd(&lcin[j], 1);
                    if (p < SL) slot_in[(size_t)dd[q] * SL + p] = ss[q];
                }
                int j2 = ss[q] - base;
                if ((unsigned)j2 < 8u) {
                    int p2 = atomicAdd(&lcout[j2], 1);
                    if (p2 < SL) slot_out[(size_t)ss[q] * SL + p2] = dd[q];
                }
            }
        }
        __syncthreads();
        if (tid < 8) {
            cnt[base + tid]  = lcin[tid];
            ocnt[base + tid] = lcout[tid];
        }
    } else {
        // W1 -> MFMA B-fragment layout (16x16x32 bf16) + y/done zero
        // frag f = nt*4+kc; lane l holds W1[k = kc*32 + (l>>4)*8 + j][nt*16 + (l&15)]
        int g = (blk - CVT_BLOCKS - NODE_BLOCKS) * 256 + tid;   // 0..2047
        int lane = g & 63, f = g >> 6;
        int nt = f >> 2, kc = f & 3;
        int col = nt * 16 + (lane & 15);
        int k0  = kc * 32 + (lane >> 4) * 8;
        uint4 o;
        o.x = pack_bf16x2(W1[(k0 + 0) * ND + col], W1[(k0 + 1) * ND + col]);
        o.y = pack_bf16x2(W1[(k0 + 2) * ND + col], W1[(k0 + 3) * ND + col]);
        o.z = pack_bf16x2(W1[(k0 + 4) * ND + col], W1[(k0 + 5) * ND + col]);
        o.w = pack_bf16x2(W1[(k0 + 6) * ND + col], W1[(k0 + 7) * ND + col]);
        ((uint4*)wf)[g] = o;
        y[2 * g] = 0.f; y[2 * g + 1] = 0.f;
        if (g == 0) *done = 0;
    }
}

// ---- N2: wsum-prep + stage edges + bf16 gather (2 batches) + MFMA + reduce
//      + vmcnt-ordered ticket; last block computes out = (1/N) y @ W2 + b2 ----
__global__ __launch_bounds__(256, 4) void k_fused(const ushort* __restrict__ xbf,
                                                  const int* __restrict__ cnt,
                                                  const int* __restrict__ ocnt,
                                                  const int* __restrict__ slot_in,
                                                  const int* __restrict__ slot_out,
                                                  const uint* __restrict__ wfrag,
                                                  const float* __restrict__ b1,
                                                  float* __restrict__ y,
                                                  int* __restrict__ done,
                                                  const float* __restrict__ W2,
                                                  const float* __restrict__ b2,
                                                  float* __restrict__ out) {
    __shared__ uint  AsU[2][32 * 68];   // bf16 A, row stride 136 bf16; 17408 B
    __shared__ int2  sEdge[ECAP];       // 12288 B (src, w-bits)
    __shared__ int   sCnt[32];
    __shared__ int   sBase[33];
    __shared__ float sDinv[32];
    __shared__ float sWn[32];
    __shared__ float yred[2][128];
    __shared__ int   sTicket;
    const int tid = threadIdx.x;

    // XCD batch-partition swizzle; block handles batches b0, b0+1 (same graph)
    const int L     = blockIdx.x;
    const int xcd   = L & (NXCD - 1);
    const int sl    = L >> 3;
    const int pair  = sl / NCHUNK;
    const int chunk = sl % NCHUNK;
    const int b0    = xcd * (BPB * PAIRS) + pair * BPB;
    const int n0    = chunk * TR;

    if (tid < 32) {
        int n = n0 + tid;
        int cr = (n < NN) ? cnt[n] : 0;
        sCnt[tid]  = min(cr, SL);
        sDinv[tid] = rsqrtf((float)(cr + 1));
    }
    if (tid < 128) { yred[0][tid] = 0.f; yred[1][tid] = 0.f; }
    __syncthreads();
    if (tid == 0) {
        int s = 0;
        for (int j = 0; j < 32; j++) { sBase[j] = s; s += sCnt[j]; }
        sBase[32] = s;
    }

    const int wv = tid >> 6, ln = tid & 63;

    // ---- per-row wsum from out-CSR: wsum = dinv*(dinv + sum rsqrt(cnt[dst]+1)) ----
    for (int ii = 0; ii < 8; ii++) {
        const int j = wv * 8 + ii;
        const int n = n0 + j;
        float part = 0.f;
        if (n < NN) {
            int oc = min(ocnt[n], SL);
            const int* op = &slot_out[(size_t)n * SL];
            for (int base = 0; base < oc; base += 64)
                if (base + ln < oc)
                    part += rsqrtf((float)(cnt[op[base + ln]] + 1));
        }
        #pragma unroll
        for (int off = 32; off; off >>= 1) part += __shfl_down(part, off, 64);
        if (ln == 0) {
            float d = sDinv[j];
            sWn[j] = (n < NN) ? d * (d + part) : 0.f;
        }
    }
    __syncthreads();
    const bool staged = (sBase[32] <= ECAP);

    // ---- stage in-edges; compute w at staging time ----
    if (staged) {
        for (int ii = 0; ii < 8; ii++) {
            int j = wv * 8 + ii;
            int c = sCnt[j];
            float dd = sDinv[j];
            const int* sp = &slot_in[(size_t)(n0 + j) * SL];
            for (int base = 0; base < c; base += 64) {
                if (base + ln < c) {
                    int sidx = sp[base + ln];
                    float w = rsqrtf((float)(cnt[sidx] + 1)) * dd;
                    sEdge[sBase[j] + base + ln] = make_int2(sidx, __float_as_int(w));
                }
            }
        }
    }
    __syncthreads();

    // ---- gather: wave owns row; lane ln owns features 2ln,2ln+1 (one u32/row) ----
    const uint* __restrict__ Xu0 = (const uint*)(xbf + (size_t)b0 * NN * ND);
    const uint* __restrict__ Xu1 = (const uint*)(xbf + (size_t)(b0 + 1) * NN * ND);
    #pragma unroll 1
    for (int ii = 0; ii < 8; ii++) {
        const int j = wv * 8 + ii;
        const int n = n0 + j;
        float2 a0 = make_float2(0.f, 0.f), a1 = a0, a0b = a0, a1b = a0;
        if (n < NN) {
            float sn = sDinv[j]; sn *= sn;
            uint u0 = Xu0[n * 64 + ln], u1 = Xu1[n * 64 + ln];
            a0.x = sn * __uint_as_float(u0 << 16);
            a0.y = sn * __uint_as_float(u0 & 0xffff0000u);
            a1.x = sn * __uint_as_float(u1 << 16);
            a1.y = sn * __uint_as_float(u1 & 0xffff0000u);
            const int c = sCnt[j];
            if (staged) {
                const int e0 = sBase[j], e1 = e0 + c;
                int e = e0;
                for (; e + 8 <= e1; e += 8) {
                    int sidx[8]; float w[8]; uint q0[8], q1[8];
                    #pragma unroll
                    for (int q = 0; q < 8; q++) {
                        int2 ed = sEdge[e + q];
                        sidx[q] = ed.x; w[q] = __int_as_float(ed.y);
                    }
                    #pragma unroll
                    for (int q = 0; q < 8; q++) {     // 16 independent 256B loads
                        q0[q] = Xu0[sidx[q] * 64 + ln];
                        q1[q] = Xu1[sidx[q] * 64 + ln];
                    }
                    #pragma unroll
                    for (int q = 0; q < 8; q++) {     // dual accumulators
                        float x0l = __uint_as_float(q0[q] << 16);
                        float x0h = __uint_as_float(q0[q] & 0xffff0000u);
                        float x1l = __uint_as_float(q1[q] << 16);
                        float x1h = __uint_as_float(q1[q] & 0xffff0000u);
                        if (q & 1) {
                            a0b.x = fmaf(w[q], x0l, a0b.x);
                            a0b.y = fmaf(w[q], x0h, a0b.y);
                            a1b.x = fmaf(w[q], x1l, a1b.x);
                            a1b.y = fmaf(w[q], x1h, a1b.y);
                        } else {
                            a0.x = fmaf(w[q], x0l, a0.x);
                            a0.y = fmaf(w[q], x0h, a0.y);
                            a1.x = fmaf(w[q], x1l, a1.x);
                            a1.y = fmaf(w[q], x1h, a1.y);
                        }
                    }
                }
                for (; e < e1; e++) {
                    int2 ed = sEdge[e];
                    float w = __int_as_float(ed.y);
                    uint u0e = Xu0[ed.x * 64 + ln], u1e = Xu1[ed.x * 64 + ln];
                    a0.x = fmaf(w, __uint_as_float(u0e << 16), a0.x);
                    a0.y = fmaf(w, __uint_as_float(u0e & 0xffff0000u), a0.y);
                    a1.x = fmaf(w, __uint_as_float(u1e << 16), a1.x);
                    a1.y = fmaf(w, __uint_as_float(u1e & 0xffff0000u), a1.y);
                }
            } else {
                const int* sp = &slot_in[(size_t)n * SL];
                float dd = sDinv[j];
                for (int e = 0; e < c; e++) {
                    int sidx = sp[e];
                    float w = rsqrtf((float)(cnt[sidx] + 1)) * dd;
                    uint u0e = Xu0[sidx * 64 + ln], u1e = Xu1[sidx * 64 + ln];
                    a0.x = fmaf(w, __uint_as_float(u0e << 16), a0.x);
                    a0.y = fmaf(w, __uint_as_float(u0e & 0xffff0000u), a0.y);
                    a1.x = fmaf(w, __uint_as_float(u1e << 16), a1.x);
                    a1.y = fmaf(w, __uint_as_float(u1e & 0xffff0000u), a1.y);
                }
            }
            a0.x += a0b.x; a0.y += a0b.y;
            a1.x += a1b.x; a1.y += a1b.y;
        }
        AsU[0][j * 68 + ln] = pack_bf16x2(a0.x, a0.y);
        AsU[1][j * 68 + ln] = pack_bf16x2(a1.x, a1.y);
    }
    __syncthreads();

    // ---- MFMA GEMM: wave wv owns n-tiles {2wv, 2wv+1}; 32 mfma per wave ----
    const int lane15 = ln & 15, quad = ln >> 4;
    f32x4 zero4 = {0.f, 0.f, 0.f, 0.f};
    f32x4 acc[2][2][2];                  // [batch][mt][nt2]
    #pragma unroll
    for (int b = 0; b < 2; b++)
        #pragma unroll
        for (int mt = 0; mt < 2; mt++)
            #pragma unroll
            for (int nt2 = 0; nt2 < 2; nt2++) acc[b][mt][nt2] = zero4;

    bf16x8 wfr[2][4];
    const bf16x8* Wf8 = (const bf16x8*)wfrag;
    #pragma unroll
    for (int nt2 = 0; nt2 < 2; nt2++)
        #pragma unroll
        for (int kc = 0; kc < 4; kc++)
            wfr[nt2][kc] = Wf8[(((2 * wv + nt2) * 4 + kc) * 64) + ln];

    const bf16x8* A8_0 = (const bf16x8*)AsU[0];   // row stride 17 frags
    const bf16x8* A8_1 = (const bf16x8*)AsU[1];
    #pragma unroll
    for (int mt = 0; mt < 2; mt++) {
        const int r = mt * 16 + lane15;
        #pragma unroll
        for (int kc = 0; kc < 4; kc++) {
            bf16x8 af0 = A8_0[r * 17 + kc * 4 + quad];
            bf16x8 af1 = A8_1[r * 17 + kc * 4 + quad];
            #pragma unroll
            for (int nt2 = 0; nt2 < 2; nt2++) {
                acc[0][mt][nt2] = __builtin_amdgcn_mfma_f32_16x16x32_bf16(
                    af0, wfr[nt2][kc], acc[0][mt][nt2], 0, 0, 0);
                acc[1][mt][nt2] = __builtin_amdgcn_mfma_f32_16x16x32_bf16(
                    af1, wfr[nt2][kc], acc[1][mt][nt2], 0, 0, 0);
            }
        }
    }

    // ---- epilogue: relu + wsum-weighted reduce (C-layout aware) ----
    #pragma unroll
    for (int nt2 = 0; nt2 < 2; nt2++) {
        int cg = (2 * wv + nt2) * 16 + lane15;
        float bias = b1[cg];
        #pragma unroll
        for (int b = 0; b < 2; b++) {
            float part = 0.f;
            #pragma unroll
            for (int mt = 0; mt < 2; mt++) {
                f32x4 a = acc[b][mt][nt2];
                #pragma unroll
                for (int r = 0; r < 4; r++) {
                    int m = mt * 16 + quad * 4 + r;
                    part = fmaf(sWn[m], fmaxf(a[r] + bias, 0.f), part);
                }
            }
            atomicAdd(&yred[b][cg], part);
        }
    }
    __syncthreads();
    // device-scope atomic adds into y (coherent at LLC, no local-L2 dirty lines)
    if (tid < 128) atomicAdd(&y[b0 * ND + tid], yred[0][tid]);
    else           atomicAdd(&y[(b0 + 1) * ND + (tid - 128)], yred[1][tid - 128]);

    // ---- ticket: drain own vmem (cheap), then relaxed device-scope increment ----
    asm volatile("s_waitcnt vmcnt(0)" ::: "memory");
    __syncthreads();                      // all waves drained their y-adds
    if (tid == 0)
        sTicket = __hip_atomic_fetch_add(done, 1, __ATOMIC_RELAXED,
                                         __HIP_MEMORY_SCOPE_AGENT);
    __syncthreads();
    if (sTicket == GRID_FUSED - 1) {
        // last block: out = (1/N) * y @ W2 + b2
        float* ysh = (float*)AsU;         // 16 KB reuse
        for (int i = tid; i < NB * ND; i += 256)
            ysh[i] = __hip_atomic_load(&y[i], __ATOMIC_RELAXED,
                                       __HIP_MEMORY_SCOPE_AGENT) * (1.f / (float)NN);
        __syncthreads();
        for (int o = tid; o < NB * ND; o += 256) {
            int bb = o >> 7, d = o & 127;
            float accO = b2[d];
            const float* yb = ysh + bb * 128;
            #pragma unroll 8
            for (int k = 0; k < 128; k++)
                accO = fmaf(yb[k], W2[k * ND + d], accO);
            out[o] = accO;
        }
    }
}

extern "C" void kernel_launch(void* const* d_in, const int* in_sizes, int n_in,
                              void* d_out, int out_size, void* d_ws, size_t ws_size,
                              hipStream_t stream) {
    (void)in_sizes; (void)n_in; (void)out_size; (void)ws_size;
    const float* X   = (const float*)d_in[0];
    const int*   src = (const int*)d_in[1];
    const int*   dst = (const int*)d_in[2];
    const float* W1  = (const float*)d_in[3];
    const float* b1  = (const float*)d_in[4];
    const float* W2  = (const float*)d_in[5];
    const float* b2  = (const float*)d_in[6];
    float* out = (float*)d_out;

    char* ws = (char*)d_ws;
    int*    cnt  = (int*)   (ws + OFF_CNT);
    int*    ocnt = (int*)   (ws + OFF_OCNT);
    float*  y    = (float*) (ws + OFF_Y);
    int*    done = (int*)   (ws + OFF_DONE);
    int*    sli  = (int*)   (ws + OFF_SLI);
    int*    slo  = (int*)   (ws + OFF_SLO);
    uint*   wfb  = (uint*)  (ws + OFF_WF);
    ushort* xbf  = (ushort*)(ws + OFF_XBF);

    k_prep<<<PREP_GRID, 256, 0, stream>>>(X, xbf, W1, wfb, src, dst,
                                          cnt, ocnt, sli, slo, y, done);
    k_fused<<<GRID_FUSED, 256, 0, stream>>>(xbf, cnt, ocnt, sli, slo, wfb, b1,
                                            y, done, W2, b2, out);
}

// Round 12
// 184.680 us; speedup vs baseline: 1.1881x; 1.1881x over previous
//
#include <hip/hip_runtime.h>

namespace {
constexpr int NB = 32;      // batch
constexpr int NN = 2000;    // nodes
constexpr int NE = 64000;   // edges
constexpr int ND = 128;     // feature dim
constexpr int TR = 32;      // tile rows
constexpr int NCHUNK = (NN + TR - 1) / TR;   // 63
constexpr int NXCD = 8;
constexpr int BPB = 2;                        // batches per block
constexpr int PAIRS = NB / (NXCD * BPB);      // 2
constexpr int GRID_FUSED = NXCD * PAIRS * NCHUNK;  // 1008
constexpr int SL = 80;      // slot stride per node (Poisson(32); P(deg>80)~1e-12)
constexpr int ECAP = 1536;  // staged in-edge cap per 32-row tile (mean 1024)

constexpr int CVT_BLOCKS  = 8000;  // 8000*256 float4 = 8.192M floats exactly
constexpr int NODE_BLOCKS = 250;   // each owns 8 nodes; atomic-free graph build
constexpr int W_BLOCKS    = 8;     // W1 prepack
constexpr int PREP_GRID   = CVT_BLOCKS + NODE_BLOCKS + W_BLOCKS;

// ---- workspace layout (bytes); every region fully written before read ----
constexpr size_t OFF_CNT  = 0;                 // int[2048]  in-degree (exclusive writes)
constexpr size_t OFF_OCNT = 8192;              // int[2048]  out-degree
constexpr size_t OFF_SLI  = 16384;             // int[NN*SL] in-edge srcs  (640 KB)
constexpr size_t OFF_SLO  = OFF_SLI + (size_t)NN * SL * 4;   // int[NN*SL] out-edge dsts
constexpr size_t OFF_WF   = OFF_SLO + (size_t)NN * SL * 4;   // bf16 W1 frags (32 KB)
constexpr size_t OFF_XBF  = OFF_WF + 32768;    // ushort[NB*NN*ND] = 16.384 MB
constexpr size_t OFF_YP   = OFF_XBF + (size_t)NB * NN * ND * 2;  // float[NB*NCHUNK*ND]

typedef __attribute__((ext_vector_type(8))) short bf16x8;
typedef __attribute__((ext_vector_type(4))) float f32x4;

// f32 -> bf16 (round-to-nearest-even), bit arithmetic; inputs finite
__device__ __forceinline__ ushort f32_to_bf16(float f) {
    uint u = __float_as_uint(f);
    u += 0x7fffu + ((u >> 16) & 1u);
    return (ushort)(u >> 16);
}
__device__ __forceinline__ uint pack_bf16x2(float lo, float hi) {
    return (uint)f32_to_bf16(lo) | ((uint)f32_to_bf16(hi) << 16);
}
} // namespace

// ---- N1: heterogeneous prep: cvt X | node-owner graph build | W prepack ----
__global__ void k_prep(const float* __restrict__ X, ushort* __restrict__ xbf,
                       const float* __restrict__ W1, uint* __restrict__ wf,
                       const int* __restrict__ src, const int* __restrict__ dst,
                       int* __restrict__ cnt, int* __restrict__ ocnt,
                       int* __restrict__ slot_in, int* __restrict__ slot_out) {
    const int blk = blockIdx.x;
    const int tid = threadIdx.x;
    if (blk < CVT_BLOCKS) {
        int i = blk * 256 + tid;              // float4 index, exact bounds
        float4 v = ((const float4*)X)[i];
        ushort4 o;
        o.x = f32_to_bf16(v.x);
        o.y = f32_to_bf16(v.y);
        o.z = f32_to_bf16(v.z);
        o.w = f32_to_bf16(v.w);
        ((ushort4*)xbf)[i] = o;
    } else if (blk < CVT_BLOCKS + NODE_BLOCKS) {
        // owns nodes [base, base+8); scans all edges; LDS cursors; NO global atomics
        const int base = (blk - CVT_BLOCKS) * 8;
        __shared__ int lcin[8], lcout[8];
        if (tid < 8) { lcin[tid] = 0; lcout[tid] = 0; }
        __syncthreads();
        const int4* s4p = (const int4*)src;
        const int4* d4p = (const int4*)dst;
        for (int i = tid; i < NE / 4; i += 256) {
            int4 s4 = s4p[i], d4 = d4p[i];
            int ss[4] = {s4.x, s4.y, s4.z, s4.w};
            int dd[4] = {d4.x, d4.y, d4.z, d4.w};
            #pragma unroll
            for (int q = 0; q < 4; q++) {
                int j = dd[q] - base;
                if ((unsigned)j < 8u) {
                    int p = atomicAdd(&lcin[j], 1);
                    if (p < SL) slot_in[(size_t)dd[q] * SL + p] = ss[q];
                }
                int j2 = ss[q] - base;
                if ((unsigned)j2 < 8u) {
                    int p2 = atomicAdd(&lcout[j2], 1);
                    if (p2 < SL) slot_out[(size_t)ss[q] * SL + p2] = dd[q];
                }
            }
        }
        __syncthreads();
        if (tid < 8) {
            cnt[base + tid]  = lcin[tid];
            ocnt[base + tid] = lcout[tid];
        }
    } else {
        // W1 -> MFMA B-fragment layout (16x16x32 bf16):
        // frag f = nt*4+kc; lane l holds W1[k = kc*32 + (l>>4)*8 + j][nt*16 + (l&15)]
        int g = (blk - CVT_BLOCKS - NODE_BLOCKS) * 256 + tid;   // 0..2047
        int lane = g & 63, f = g >> 6;
        int nt = f >> 2, kc = f & 3;
        int col = nt * 16 + (lane & 15);
        int k0  = kc * 32 + (lane >> 4) * 8;
        uint4 o;
        o.x = pack_bf16x2(W1[(k0 + 0) * ND + col], W1[(k0 + 1) * ND + col]);
        o.y = pack_bf16x2(W1[(k0 + 2) * ND + col], W1[(k0 + 3) * ND + col]);
        o.z = pack_bf16x2(W1[(k0 + 4) * ND + col], W1[(k0 + 5) * ND + col]);
        o.w = pack_bf16x2(W1[(k0 + 6) * ND + col], W1[(k0 + 7) * ND + col]);
        ((uint4*)wf)[g] = o;
    }
}

// ---- N2: wsum-prep + stage edges + bf16 gather (2 batches) + MFMA + reduce ----
__global__ __launch_bounds__(256, 4) void k_fused(const ushort* __restrict__ xbf,
                                                  const int* __restrict__ cnt,
                                                  const int* __restrict__ ocnt,
                                                  const int* __restrict__ slot_in,
                                                  const int* __restrict__ slot_out,
                                                  const uint* __restrict__ wfrag,
                                                  const float* __restrict__ b1,
                                                  float* __restrict__ ypart) {
    __shared__ uint  AsU[2][32 * 68];   // bf16 A, row stride 136 bf16; 17408 B
    __shared__ int2  sEdge[ECAP];       // 12288 B (src, w-bits)
    __shared__ int   sCnt[32];
    __shared__ int   sBase[33];
    __shared__ float sDinv[32];
    __shared__ float sWn[32];
    __shared__ float yred[2][128];
    const int tid = threadIdx.x;

    // XCD batch-partition swizzle; block handles batches b0, b0+1 (same graph)
    const int L     = blockIdx.x;
    const int xcd   = L & (NXCD - 1);
    const int sl    = L >> 3;
    const int pair  = sl / NCHUNK;
    const int chunk = sl % NCHUNK;
    const int b0    = xcd * (BPB * PAIRS) + pair * BPB;
    const int n0    = chunk * TR;

    if (tid < 32) {
        int n = n0 + tid;
        int cr = (n < NN) ? cnt[n] : 0;
        sCnt[tid]  = min(cr, SL);
        sDinv[tid] = rsqrtf((float)(cr + 1));
    }
    if (tid < 128) { yred[0][tid] = 0.f; yred[1][tid] = 0.f; }
    __syncthreads();
    if (tid == 0) {
        int s = 0;
        for (int j = 0; j < 32; j++) { sBase[j] = s; s += sCnt[j]; }
        sBase[32] = s;
    }

    const int wv = tid >> 6, ln = tid & 63;

    // ---- per-row wsum from out-CSR: wsum = dinv*(dinv + sum rsqrt(cnt[dst]+1)) ----
    for (int ii = 0; ii < 8; ii++) {
        const int j = wv * 8 + ii;
        const int n = n0 + j;
        float part = 0.f;
        if (n < NN) {
            int oc = min(ocnt[n], SL);
            const int* op = &slot_out[(size_t)n * SL];
            for (int base = 0; base < oc; base += 64)
                if (base + ln < oc)
                    part += rsqrtf((float)(cnt[op[base + ln]] + 1));
        }
        #pragma unroll
        for (int off = 32; off; off >>= 1) part += __shfl_down(part, off, 64);
        if (ln == 0) {
            float d = sDinv[j];
            sWn[j] = (n < NN) ? d * (d + part) : 0.f;
        }
    }
    __syncthreads();
    const bool staged = (sBase[32] <= ECAP);

    // ---- stage in-edges; compute w at staging time ----
    if (staged) {
        for (int ii = 0; ii < 8; ii++) {
            int j = wv * 8 + ii;
            int c = sCnt[j];
            float dd = sDinv[j];
            const int* sp = &slot_in[(size_t)(n0 + j) * SL];
            for (int base = 0; base < c; base += 64) {
                if (base + ln < c) {
                    int sidx = sp[base + ln];
                    float w = rsqrtf((float)(cnt[sidx] + 1)) * dd;
                    sEdge[sBase[j] + base + ln] = make_int2(sidx, __float_as_int(w));
                }
            }
        }
    }
    __syncthreads();

    // ---- gather: wave owns row; lane ln owns features 2ln,2ln+1 (one u32/row) ----
    const uint* __restrict__ Xu0 = (const uint*)(xbf + (size_t)b0 * NN * ND);
    const uint* __restrict__ Xu1 = (const uint*)(xbf + (size_t)(b0 + 1) * NN * ND);
    #pragma unroll 1
    for (int ii = 0; ii < 8; ii++) {
        const int j = wv * 8 + ii;
        const int n = n0 + j;
        float2 a0 = make_float2(0.f, 0.f), a1 = a0, a0b = a0, a1b = a0;
        if (n < NN) {
            float sn = sDinv[j]; sn *= sn;
            uint u0 = Xu0[n * 64 + ln], u1 = Xu1[n * 64 + ln];
            a0.x = sn * __uint_as_float(u0 << 16);
            a0.y = sn * __uint_as_float(u0 & 0xffff0000u);
            a1.x = sn * __uint_as_float(u1 << 16);
            a1.y = sn * __uint_as_float(u1 & 0xffff0000u);
            const int c = sCnt[j];
            if (staged) {
                const int e0 = sBase[j], e1 = e0 + c;
                int e = e0;
                for (; e + 8 <= e1; e += 8) {
                    int sidx[8]; float w[8]; uint q0[8], q1[8];
                    #pragma unroll
                    for (int q = 0; q < 8; q++) {
                        int2 ed = sEdge[e + q];
                        sidx[q] = ed.x; w[q] = __int_as_float(ed.y);
                    }
                    #pragma unroll
                    for (int q = 0; q < 8; q++) {     // 16 independent 256B loads
                        q0[q] = Xu0[sidx[q] * 64 + ln];
                        q1[q] = Xu1[sidx[q] * 64 + ln];
                    }
                    #pragma unroll
                    for (int q = 0; q < 8; q++) {     // dual accumulators
                        float x0l = __uint_as_float(q0[q] << 16);
                        float x0h = __uint_as_float(q0[q] & 0xffff0000u);
                        float x1l = __uint_as_float(q1[q] << 16);
                        float x1h = __uint_as_float(q1[q] & 0xffff0000u);
                        if (q & 1) {
                            a0b.x = fmaf(w[q], x0l, a0b.x);
                            a0b.y = fmaf(w[q], x0h, a0b.y);
                            a1b.x = fmaf(w[q], x1l, a1b.x);
                            a1b.y = fmaf(w[q], x1h, a1b.y);
                        } else {
                            a0.x = fmaf(w[q], x0l, a0.x);
                            a0.y = fmaf(w[q], x0h, a0.y);
                            a1.x = fmaf(w[q], x1l, a1.x);
                            a1.y = fmaf(w[q], x1h, a1.y);
                        }
                    }
                }
                for (; e < e1; e++) {
                    int2 ed = sEdge[e];
                    float w = __int_as_float(ed.y);
                    uint u0e = Xu0[ed.x * 64 + ln], u1e = Xu1[ed.x * 64 + ln];
                    a0.x = fmaf(w, __uint_as_float(u0e << 16), a0.x);
                    a0.y = fmaf(w, __uint_as_float(u0e & 0xffff0000u), a0.y);
                    a1.x = fmaf(w, __uint_as_float(u1e << 16), a1.x);
                    a1.y = fmaf(w, __uint_as_float(u1e & 0xffff0000u), a1.y);
                }
            } else {
                const int* sp = &slot_in[(size_t)n * SL];
                float dd = sDinv[j];
                for (int e = 0; e < c; e++) {
                    int sidx = sp[e];
                    float w = rsqrtf((float)(cnt[sidx] + 1)) * dd;
                    uint u0e = Xu0[sidx * 64 + ln], u1e = Xu1[sidx * 64 + ln];
                    a0.x = fmaf(w, __uint_as_float(u0e << 16), a0.x);
                    a0.y = fmaf(w, __uint_as_float(u0e & 0xffff0000u), a0.y);
                    a1.x = fmaf(w, __uint_as_float(u1e << 16), a1.x);
                    a1.y = fmaf(w, __uint_as_float(u1e & 0xffff0000u), a1.y);
                }
            }
            a0.x += a0b.x; a0.y += a0b.y;
            a1.x += a1b.x; a1.y += a1b.y;
        }
        AsU[0][j * 68 + ln] = pack_bf16x2(a0.x, a0.y);
        AsU[1][j * 68 + ln] = pack_bf16x2(a1.x, a1.y);
    }
    __syncthreads();

    // ---- MFMA GEMM: wave wv owns n-tiles {2wv, 2wv+1}; 32 mfma per wave ----
    const int lane15 = ln & 15, quad = ln >> 4;
    f32x4 zero4 = {0.f, 0.f, 0.f, 0.f};
    f32x4 acc[2][2][2];                  // [batch][mt][nt2]
    #pragma unroll
    for (int b = 0; b < 2; b++)
        #pragma unroll
        for (int mt = 0; mt < 2; mt++)
            #pragma unroll
            for (int nt2 = 0; nt2 < 2; nt2++) acc[b][mt][nt2] = zero4;

    bf16x8 wfr[2][4];
    const bf16x8* Wf8 = (const bf16x8*)wfrag;
    #pragma unroll
    for (int nt2 = 0; nt2 < 2; nt2++)
        #pragma unroll
        for (int kc = 0; kc < 4; kc++)
            wfr[nt2][kc] = Wf8[(((2 * wv + nt2) * 4 + kc) * 64) + ln];

    const bf16x8* A8_0 = (const bf16x8*)AsU[0];   // row stride 17 frags
    const bf16x8* A8_1 = (const bf16x8*)AsU[1];
    #pragma unroll
    for (int mt = 0; mt < 2; mt++) {
        const int r = mt * 16 + lane15;
        #pragma unroll
        for (int kc = 0; kc < 4; kc++) {
            bf16x8 af0 = A8_0[r * 17 + kc * 4 + quad];
            bf16x8 af1 = A8_1[r * 17 + kc * 4 + quad];
            #pragma unroll
            for (int nt2 = 0; nt2 < 2; nt2++) {
                acc[0][mt][nt2] = __builtin_amdgcn_mfma_f32_16x16x32_bf16(
                    af0, wfr[nt2][kc], acc[0][mt][nt2], 0, 0, 0);
                acc[1][mt][nt2] = __builtin_amdgcn_mfma_f32_16x16x32_bf16(
                    af1, wfr[nt2][kc], acc[1][mt][nt2], 0, 0, 0);
            }
        }
    }

    // ---- epilogue: relu + wsum-weighted reduce (C-layout aware) ----
    #pragma unroll
    for (int nt2 = 0; nt2 < 2; nt2++) {
        int cg = (2 * wv + nt2) * 16 + lane15;
        float bias = b1[cg];
        #pragma unroll
        for (int b = 0; b < 2; b++) {
            float part = 0.f;
            #pragma unroll
            for (int mt = 0; mt < 2; mt++) {
                f32x4 a = acc[b][mt][nt2];
                #pragma unroll
                for (int r = 0; r < 4; r++) {
                    int m = mt * 16 + quad * 4 + r;
                    part = fmaf(sWn[m], fmaxf(a[r] + bias, 0.f), part);
                }
            }
            atomicAdd(&yred[b][cg], part);
        }
    }
    __syncthreads();
    if (tid < 128)
        ypart[((size_t)b0 * NCHUNK + chunk) * ND + tid] = yred[0][tid];
    else
        ypart[((size_t)(b0 + 1) * NCHUNK + chunk) * ND + (tid - 128)] = yred[1][tid - 128];
}

// ---- N3: out[b,:] = (1/N) * (sum_chunk ypart[b,chunk,:]) @ W2 + b2 ----
__global__ __launch_bounds__(128) void k_out(const float* __restrict__ ypart,
                                             const float* __restrict__ W2,
                                             const float* __restrict__ b2,
                                             float* __restrict__ out) {
    __shared__ float ys[128];
    const int b = blockIdx.x;
    const int d = threadIdx.x;
    float s = 0.f;
    for (int c = 0; c < NCHUNK; c++)
        s += ypart[((size_t)b * NCHUNK + c) * ND + d];
    ys[d] = s * (1.f / (float)NN);
    __syncthreads();
    float acc = b2[d];
    #pragma unroll 8
    for (int k = 0; k < 128; k++)
        acc = fmaf(ys[k], W2[k * ND + d], acc);
    out[b * ND + d] = acc;
}

extern "C" void kernel_launch(void* const* d_in, const int* in_sizes, int n_in,
                              void* d_out, int out_size, void* d_ws, size_t ws_size,
                              hipStream_t stream) {
    (void)in_sizes; (void)n_in; (void)out_size; (void)ws_size;
    const float* X   = (const float*)d_in[0];
    const int*   src = (const int*)d_in[1];
    const int*   dst = (const int*)d_in[2];
    const float* W1  = (const float*)d_in[3];
    const float* b1  = (const float*)d_in[4];
    const float* W2  = (const float*)d_in[5];
    const float* b2  = (const float*)d_in[6];
    float* out = (float*)d_out;

    char* ws = (char*)d_ws;
    int*    cnt   = (int*)   (ws + OFF_CNT);
    int*    ocnt  = (int*)   (ws + OFF_OCNT);
    int*    sli   = (int*)   (ws + OFF_SLI);
    int*    slo   = (int*)   (ws + OFF_SLO);
    uint*   wfb   = (uint*)  (ws + OFF_WF);
    ushort* xbf   = (ushort*)(ws + OFF_XBF);
    float*  ypart = (float*) (ws + OFF_YP);

    k_prep<<<PREP_GRID, 256, 0, stream>>>(X, xbf, W1, wfb, src, dst,
                                          cnt, ocnt, sli, slo);
    k_fused<<<GRID_FUSED, 256, 0, stream>>>(xbf, cnt, ocnt, sli, slo, wfb, b1, ypart);
    k_out<<<NB, 128, 0, stream>>>(ypart, W2, b2, out);
}

// Round 13
// 179.385 us; speedup vs baseline: 1.2231x; 1.0295x over previous
//
#include <hip/hip_runtime.h>

namespace {
constexpr int NB = 32;      // batch
constexpr int NN = 2000;    // nodes
constexpr int NE = 64000;   // edges
constexpr int ND = 128;     // feature dim
constexpr int TR = 32;      // tile rows
constexpr int NCHUNK = (NN + TR - 1) / TR;   // 63
constexpr int NXCD = 8;
constexpr int BPB = 2;                        // batches per block
constexpr int PAIRS = NB / (NXCD * BPB);      // 2
constexpr int GRID_FUSED = NXCD * PAIRS * NCHUNK;  // 1008
constexpr int SL = 80;      // slot stride per node (Poisson(32); P(deg>80)~1e-12)

constexpr int CVT_BLOCKS  = 8000;  // 8000*256 float4 = 8.192M floats exactly
constexpr int W_BLOCKS    = 8;     // W1 prepack
constexpr int EDGE_BLOCKS = 250;   // 250*256 = 64000 edges exactly
constexpr int FILL_GRID   = CVT_BLOCKS + W_BLOCKS + EDGE_BLOCKS;

// ---- workspace layout (bytes) ----
constexpr size_t OFF_CNT  = 0;                 // int[2048]  (memset 0)
constexpr size_t OFF_OCNT = 8192;              // int[2048]  (memset 0)
constexpr size_t OFF_SLI  = 16384;             // int[NN*SL] in-edge srcs  (640 KB)
constexpr size_t OFF_SLO  = OFF_SLI + (size_t)NN * SL * 4;   // int[NN*SL] out-edge dsts
constexpr size_t OFF_WF   = OFF_SLO + (size_t)NN * SL * 4;   // bf16 W1 frags (32 KB)
constexpr size_t OFF_XBF  = OFF_WF + 32768;    // ushort[NB*NN*ND] = 16.384 MB
constexpr size_t OFF_YP   = OFF_XBF + (size_t)NB * NN * ND * 2;  // float[NB*NCHUNK*ND]
constexpr size_t MEMSET_BYTES = 16384;         // cnt + ocnt

typedef __attribute__((ext_vector_type(8))) short bf16x8;
typedef __attribute__((ext_vector_type(4))) float f32x4;

// f32 -> bf16 (round-to-nearest-even), bit arithmetic; inputs finite
__device__ __forceinline__ ushort f32_to_bf16(float f) {
    uint u = __float_as_uint(f);
    u += 0x7fffu + ((u >> 16) & 1u);
    return (ushort)(u >> 16);
}
__device__ __forceinline__ uint pack_bf16x2(float lo, float hi) {
    return (uint)f32_to_bf16(lo) | ((uint)f32_to_bf16(hi) << 16);
}
} // namespace

// ---- N2: heterogeneous: cvt X->bf16 | W1 frag prepack | edge-parallel slot fill ----
__global__ void k_fill(const float* __restrict__ X, ushort* __restrict__ xbf,
                       const float* __restrict__ W1, uint* __restrict__ wf,
                       const int* __restrict__ src, const int* __restrict__ dst,
                       int* __restrict__ cnt, int* __restrict__ ocnt,
                       int* __restrict__ slot_in, int* __restrict__ slot_out) {
    const int blk = blockIdx.x;
    const int tid = threadIdx.x;
    if (blk < CVT_BLOCKS) {
        int i = blk * 256 + tid;              // float4 index, exact bounds
        float4 v = ((const float4*)X)[i];
        ushort4 o;
        o.x = f32_to_bf16(v.x);
        o.y = f32_to_bf16(v.y);
        o.z = f32_to_bf16(v.z);
        o.w = f32_to_bf16(v.w);
        ((ushort4*)xbf)[i] = o;
    } else if (blk < CVT_BLOCKS + W_BLOCKS) {
        // W1 -> MFMA B-fragment layout (16x16x32 bf16):
        // frag f = nt*4+kc; lane l holds W1[k = kc*32 + (l>>4)*8 + j][nt*16 + (l&15)]
        int g = (blk - CVT_BLOCKS) * 256 + tid;   // 0..2047
        int lane = g & 63, f = g >> 6;
        int nt = f >> 2, kc = f & 3;
        int col = nt * 16 + (lane & 15);
        int k0  = kc * 32 + (lane >> 4) * 8;
        uint4 o;
        o.x = pack_bf16x2(W1[(k0 + 0) * ND + col], W1[(k0 + 1) * ND + col]);
        o.y = pack_bf16x2(W1[(k0 + 2) * ND + col], W1[(k0 + 3) * ND + col]);
        o.z = pack_bf16x2(W1[(k0 + 4) * ND + col], W1[(k0 + 5) * ND + col]);
        o.w = pack_bf16x2(W1[(k0 + 6) * ND + col], W1[(k0 + 7) * ND + col]);
        ((uint4*)wf)[g] = o;
    } else {
        int e = (blk - CVT_BLOCKS - W_BLOCKS) * 256 + tid;   // exact bounds
        int s = src[e], d = dst[e];
        int p = atomicAdd(&cnt[d], 1);
        if (p < SL) slot_in[(size_t)d * SL + p] = s;
        int q = atomicAdd(&ocnt[s], 1);
        if (q < SL) slot_out[(size_t)s * SL + q] = d;
    }
}

// ---- N3: gather (slots direct, w inline) + wsum + MFMA + weighted reduce ----
__global__ __launch_bounds__(256, 4) void k_fused(const ushort* __restrict__ xbf,
                                                  const int* __restrict__ cnt,
                                                  const int* __restrict__ ocnt,
                                                  const int* __restrict__ slot_in,
                                                  const int* __restrict__ slot_out,
                                                  const uint* __restrict__ wfrag,
                                                  const float* __restrict__ b1,
                                                  float* __restrict__ ypart) {
    __shared__ uint  AsU[2][32 * 68];   // bf16 A, row stride 136 bf16; 17408 B
    __shared__ int   sCnt[32];
    __shared__ float sDinv[32];
    __shared__ float sWn[32];
    __shared__ float yred[2][128];
    const int tid = threadIdx.x;

    // XCD batch-partition swizzle; block handles batches b0, b0+1 (same graph)
    const int L     = blockIdx.x;
    const int xcd   = L & (NXCD - 1);
    const int sl    = L >> 3;
    const int pair  = sl / NCHUNK;
    const int chunk = sl % NCHUNK;
    const int b0    = xcd * (BPB * PAIRS) + pair * BPB;
    const int n0    = chunk * TR;

    if (tid < 32) {
        int n = n0 + tid;
        int cr = (n < NN) ? cnt[n] : 0;
        sCnt[tid]  = min(cr, SL);
        sDinv[tid] = rsqrtf((float)(cr + 1));
    }
    if (tid < 128) { yred[0][tid] = 0.f; yred[1][tid] = 0.f; }
    __syncthreads();

    const int wv = tid >> 6, ln = tid & 63;

    // ---- gather: wave owns row; lane ln owns features 2ln,2ln+1 (one u32/row);
    //      slot indices read via wave-uniform (scalar-cache) loads; w inline ----
    const uint* __restrict__ Xu0 = (const uint*)(xbf + (size_t)b0 * NN * ND);
    const uint* __restrict__ Xu1 = (const uint*)(xbf + (size_t)(b0 + 1) * NN * ND);
    #pragma unroll 1
    for (int ii = 0; ii < 8; ii++) {
        const int j = wv * 8 + ii;
        const int n = n0 + j;
        float2 a0 = make_float2(0.f, 0.f), a1 = a0, a0b = a0, a1b = a0;
        if (n < NN) {
            const float dd = sDinv[j];
            float sn = dd * dd;
            uint u0 = Xu0[n * 64 + ln], u1 = Xu1[n * 64 + ln];
            a0.x = sn * __uint_as_float(u0 << 16);
            a0.y = sn * __uint_as_float(u0 & 0xffff0000u);
            a1.x = sn * __uint_as_float(u1 << 16);
            a1.y = sn * __uint_as_float(u1 & 0xffff0000u);
            const int c = sCnt[j];
            const int* sp = &slot_in[(size_t)n * SL];
            int e = 0;
            for (; e + 8 <= c; e += 8) {
                int sidx[8]; float w[8]; uint q0[8], q1[8];
                #pragma unroll
                for (int q = 0; q < 8; q++) sidx[q] = sp[e + q];   // uniform -> s_load
                #pragma unroll
                for (int q = 0; q < 8; q++) {          // 16 independent 256B loads
                    q0[q] = Xu0[sidx[q] * 64 + ln];
                    q1[q] = Xu1[sidx[q] * 64 + ln];
                }
                #pragma unroll
                for (int q = 0; q < 8; q++)
                    w[q] = rsqrtf((float)(cnt[sidx[q]] + 1)) * dd;
                #pragma unroll
                for (int q = 0; q < 8; q++) {          // dual accumulators
                    float x0l = __uint_as_float(q0[q] << 16);
                    float x0h = __uint_as_float(q0[q] & 0xffff0000u);
                    float x1l = __uint_as_float(q1[q] << 16);
                    float x1h = __uint_as_float(q1[q] & 0xffff0000u);
                    if (q & 1) {
                        a0b.x = fmaf(w[q], x0l, a0b.x);
                        a0b.y = fmaf(w[q], x0h, a0b.y);
                        a1b.x = fmaf(w[q], x1l, a1b.x);
                        a1b.y = fmaf(w[q], x1h, a1b.y);
                    } else {
                        a0.x = fmaf(w[q], x0l, a0.x);
                        a0.y = fmaf(w[q], x0h, a0.y);
                        a1.x = fmaf(w[q], x1l, a1.x);
                        a1.y = fmaf(w[q], x1h, a1.y);
                    }
                }
            }
            for (; e < c; e++) {
                int sidx = sp[e];
                float w = rsqrtf((float)(cnt[sidx] + 1)) * dd;
                uint u0e = Xu0[sidx * 64 + ln], u1e = Xu1[sidx * 64 + ln];
                a0.x = fmaf(w, __uint_as_float(u0e << 16), a0.x);
                a0.y = fmaf(w, __uint_as_float(u0e & 0xffff0000u), a0.y);
                a1.x = fmaf(w, __uint_as_float(u1e << 16), a1.x);
                a1.y = fmaf(w, __uint_as_float(u1e & 0xffff0000u), a1.y);
            }
            a0.x += a0b.x; a0.y += a0b.y;
            a1.x += a1b.x; a1.y += a1b.y;
        }
        AsU[0][j * 68 + ln] = pack_bf16x2(a0.x, a0.y);
        AsU[1][j * 68 + ln] = pack_bf16x2(a1.x, a1.y);
    }

    // ---- per-row wsum from out-CSR (independent of As; hides behind gather drain) ----
    for (int ii = 0; ii < 8; ii++) {
        const int j = wv * 8 + ii;
        const int n = n0 + j;
        float part = 0.f;
        if (n < NN) {
            int oc = min(ocnt[n], SL);
            const int* op = &slot_out[(size_t)n * SL];
            for (int base = 0; base < oc; base += 64)
                if (base + ln < oc)
                    part += rsqrtf((float)(cnt[op[base + ln]] + 1));
        }
        #pragma unroll
        for (int off = 32; off; off >>= 1) part += __shfl_down(part, off, 64);
        if (ln == 0) {
            float d = sDinv[j];
            sWn[j] = (n < NN) ? d * (d + part) : 0.f;
        }
    }
    __syncthreads();

    // ---- MFMA GEMM: wave wv owns n-tiles {2wv, 2wv+1}; 32 mfma per wave ----
    const int lane15 = ln & 15, quad = ln >> 4;
    f32x4 zero4 = {0.f, 0.f, 0.f, 0.f};
    f32x4 acc[2][2][2];                  // [batch][mt][nt2]
    #pragma unroll
    for (int b = 0; b < 2; b++)
        #pragma unroll
        for (int mt = 0; mt < 2; mt++)
            #pragma unroll
            for (int nt2 = 0; nt2 < 2; nt2++) acc[b][mt][nt2] = zero4;

    bf16x8 wfr[2][4];
    const bf16x8* Wf8 = (const bf16x8*)wfrag;
    #pragma unroll
    for (int nt2 = 0; nt2 < 2; nt2++)
        #pragma unroll
        for (int kc = 0; kc < 4; kc++)
            wfr[nt2][kc] = Wf8[(((2 * wv + nt2) * 4 + kc) * 64) + ln];

    const bf16x8* A8_0 = (const bf16x8*)AsU[0];   // row stride 17 frags
    const bf16x8* A8_1 = (const bf16x8*)AsU[1];
    #pragma unroll
    for (int mt = 0; mt < 2; mt++) {
        const int r = mt * 16 + lane15;
        #pragma unroll
        for (int kc = 0; kc < 4; kc++) {
            bf16x8 af0 = A8_0[r * 17 + kc * 4 + quad];
            bf16x8 af1 = A8_1[r * 17 + kc * 4 + quad];
            #pragma unroll
            for (int nt2 = 0; nt2 < 2; nt2++) {
                acc[0][mt][nt2] = __builtin_amdgcn_mfma_f32_16x16x32_bf16(
                    af0, wfr[nt2][kc], acc[0][mt][nt2], 0, 0, 0);
                acc[1][mt][nt2] = __builtin_amdgcn_mfma_f32_16x16x32_bf16(
                    af1, wfr[nt2][kc], acc[1][mt][nt2], 0, 0, 0);
            }
        }
    }

    // ---- epilogue: relu + wsum-weighted reduce (C-layout aware) ----
    #pragma unroll
    for (int nt2 = 0; nt2 < 2; nt2++) {
        int cg = (2 * wv + nt2) * 16 + lane15;
        float bias = b1[cg];
        #pragma unroll
        for (int b = 0; b < 2; b++) {
            float part = 0.f;
            #pragma unroll
            for (int mt = 0; mt < 2; mt++) {
                f32x4 a = acc[b][mt][nt2];
                #pragma unroll
                for (int r = 0; r < 4; r++) {
                    int m = mt * 16 + quad * 4 + r;
                    part = fmaf(sWn[m], fmaxf(a[r] + bias, 0.f), part);
                }
            }
            atomicAdd(&yred[b][cg], part);
        }
    }
    __syncthreads();
    if (tid < 128)
        ypart[((size_t)b0 * NCHUNK + chunk) * ND + tid] = yred[0][tid];
    else
        ypart[((size_t)(b0 + 1) * NCHUNK + chunk) * ND + (tid - 128)] = yred[1][tid - 128];
}

// ---- N4: out[b,:] = (1/N) * (sum_chunk ypart[b,chunk,:]) @ W2 + b2 ----
__global__ __launch_bounds__(128) void k_out(const float* __restrict__ ypart,
                                             const float* __restrict__ W2,
                                             const float* __restrict__ b2,
                                             float* __restrict__ out) {
    __shared__ float ys[128];
    const int b = blockIdx.x;
    const int d = threadIdx.x;
    float s = 0.f;
    for (int c = 0; c < NCHUNK; c++)
        s += ypart[((size_t)b * NCHUNK + c) * ND + d];
    ys[d] = s * (1.f / (float)NN);
    __syncthreads();
    float acc = b2[d];
    #pragma unroll 8
    for (int k = 0; k < 128; k++)
        acc = fmaf(ys[k], W2[k * ND + d], acc);
    out[b * ND + d] = acc;
}

extern "C" void kernel_launch(void* const* d_in, const int* in_sizes, int n_in,
                              void* d_out, int out_size, void* d_ws, size_t ws_size,
                              hipStream_t stream) {
    (void)in_sizes; (void)n_in; (void)out_size; (void)ws_size;
    const float* X   = (const float*)d_in[0];
    const int*   src = (const int*)d_in[1];
    const int*   dst = (const int*)d_in[2];
    const float* W1  = (const float*)d_in[3];
    const float* b1  = (const float*)d_in[4];
    const float* W2  = (const float*)d_in[5];
    const float* b2  = (const float*)d_in[6];
    float* out = (float*)d_out;

    char* ws = (char*)d_ws;
    int*    cnt   = (int*)   (ws + OFF_CNT);
    int*    ocnt  = (int*)   (ws + OFF_OCNT);
    int*    sli   = (int*)   (ws + OFF_SLI);
    int*    slo   = (int*)   (ws + OFF_SLO);
    uint*   wfb   = (uint*)  (ws + OFF_WF);
    ushort* xbf   = (ushort*)(ws + OFF_XBF);
    float*  ypart = (float*) (ws + OFF_YP);

    (void)hipMemsetAsync(ws, 0, MEMSET_BYTES, stream);            // cnt + ocnt
    k_fill<<<FILL_GRID, 256, 0, stream>>>(X, xbf, W1, wfb, src, dst,
                                          cnt, ocnt, sli, slo);
    k_fused<<<GRID_FUSED, 256, 0, stream>>>(xbf, cnt, ocnt, sli, slo, wfb, b1, ypart);
    k_out<<<NB, 128, 0, stream>>>(ypart, W2, b2, out);
}

// Round 14
// 164.827 us; speedup vs baseline: 1.3312x; 1.0883x over previous
//
#include <hip/hip_runtime.h>

namespace {
constexpr int NB = 32;      // batch
constexpr int NN = 2000;    // nodes
constexpr int NE = 64000;   // edges
constexpr int ND = 128;     // feature dim
constexpr int TR = 32;      // tile rows
constexpr int NCHUNK = (NN + TR - 1) / TR;   // 63
constexpr int NXCD = 8;
constexpr int BPB = 2;                        // batches per block
constexpr int PAIRS = NB / (NXCD * BPB);      // 2
constexpr int GRID_FUSED = NXCD * PAIRS * NCHUNK;  // 1008
constexpr int SL = 80;      // slot stride per node (Poisson(32); P(deg>80)~1e-12)
constexpr int ECAP = 1536;  // staged in-edge cap per 32-row tile (mean 1024)

constexpr int CVT_BLOCKS  = 8000;  // 8000*256 float4 = 8.192M floats exactly
constexpr int W_BLOCKS    = 8;     // W1 prepack
constexpr int EDGE_BLOCKS = 250;   // 250*256 = 64000 edges exactly
constexpr int FILL_GRID   = CVT_BLOCKS + W_BLOCKS + EDGE_BLOCKS;

// ---- workspace layout (bytes) ----
constexpr size_t OFF_CNT  = 0;                 // int[2048]  (memset 0)
constexpr size_t OFF_OCNT = 8192;              // int[2048]  (memset 0)
constexpr size_t OFF_SLI  = 16384;             // int[NN*SL] in-edge srcs  (640 KB)
constexpr size_t OFF_SLO  = OFF_SLI + (size_t)NN * SL * 4;   // int[NN*SL] out-edge dsts
constexpr size_t OFF_WF   = OFF_SLO + (size_t)NN * SL * 4;   // bf16 W1 frags (32 KB)
constexpr size_t OFF_XBF  = OFF_WF + 32768;    // ushort[NB*NN*ND] = 16.384 MB
constexpr size_t OFF_YP   = OFF_XBF + (size_t)NB * NN * ND * 2;  // float[NB*NCHUNK*ND]
constexpr size_t MEMSET_BYTES = 16384;         // cnt + ocnt

typedef __attribute__((ext_vector_type(8))) short bf16x8;
typedef __attribute__((ext_vector_type(4))) float f32x4;

// f32 -> bf16 (round-to-nearest-even), bit arithmetic; inputs finite
__device__ __forceinline__ ushort f32_to_bf16(float f) {
    uint u = __float_as_uint(f);
    u += 0x7fffu + ((u >> 16) & 1u);
    return (ushort)(u >> 16);
}
__device__ __forceinline__ uint pack_bf16x2(float lo, float hi) {
    return (uint)f32_to_bf16(lo) | ((uint)f32_to_bf16(hi) << 16);
}
} // namespace

// ---- N2: heterogeneous: cvt X->bf16 | W1 frag prepack | edge-parallel slot fill ----
__global__ void k_fill(const float* __restrict__ X, ushort* __restrict__ xbf,
                       const float* __restrict__ W1, uint* __restrict__ wf,
                       const int* __restrict__ src, const int* __restrict__ dst,
                       int* __restrict__ cnt, int* __restrict__ ocnt,
                       int* __restrict__ slot_in, int* __restrict__ slot_out) {
    const int blk = blockIdx.x;
    const int tid = threadIdx.x;
    if (blk < CVT_BLOCKS) {
        int i = blk * 256 + tid;              // float4 index, exact bounds
        float4 v = ((const float4*)X)[i];
        ushort4 o;
        o.x = f32_to_bf16(v.x);
        o.y = f32_to_bf16(v.y);
        o.z = f32_to_bf16(v.z);
        o.w = f32_to_bf16(v.w);
        ((ushort4*)xbf)[i] = o;
    } else if (blk < CVT_BLOCKS + W_BLOCKS) {
        // W1 -> MFMA B-fragment layout (16x16x32 bf16):
        // frag f = nt*4+kc; lane l holds W1[k = kc*32 + (l>>4)*8 + j][nt*16 + (l&15)]
        int g = (blk - CVT_BLOCKS) * 256 + tid;   // 0..2047
        int lane = g & 63, f = g >> 6;
        int nt = f >> 2, kc = f & 3;
        int col = nt * 16 + (lane & 15);
        int k0  = kc * 32 + (lane >> 4) * 8;
        uint4 o;
        o.x = pack_bf16x2(W1[(k0 + 0) * ND + col], W1[(k0 + 1) * ND + col]);
        o.y = pack_bf16x2(W1[(k0 + 2) * ND + col], W1[(k0 + 3) * ND + col]);
        o.z = pack_bf16x2(W1[(k0 + 4) * ND + col], W1[(k0 + 5) * ND + col]);
        o.w = pack_bf16x2(W1[(k0 + 6) * ND + col], W1[(k0 + 7) * ND + col]);
        ((uint4*)wf)[g] = o;
    } else {
        int e = (blk - CVT_BLOCKS - W_BLOCKS) * 256 + tid;   // exact bounds
        int s = src[e], d = dst[e];
        int p = atomicAdd(&cnt[d], 1);
        if (p < SL) slot_in[(size_t)d * SL + p] = s;
        int q = atomicAdd(&ocnt[s], 1);
        if (q < SL) slot_out[(size_t)s * SL + q] = d;
    }
}

// ---- N3: wsum + stage edges + bf16 gather (2 batches) + MFMA + weighted reduce ----
__global__ __launch_bounds__(256, 4) void k_fused(const ushort* __restrict__ xbf,
                                                  const int* __restrict__ cnt,
                                                  const int* __restrict__ ocnt,
                                                  const int* __restrict__ slot_in,
                                                  const int* __restrict__ slot_out,
                                                  const uint* __restrict__ wfrag,
                                                  const float* __restrict__ b1,
                                                  float* __restrict__ ypart) {
    __shared__ uint  AsU[2][32 * 68];   // bf16 A, row stride 136 bf16; 17408 B
    __shared__ int2  sEdge[ECAP];       // 12288 B (src, w-bits)
    __shared__ int   sCnt[32];
    __shared__ int   sBase[33];
    __shared__ float sDinv[32];
    __shared__ float sWn[32];
    __shared__ float yred[2][128];
    const int tid = threadIdx.x;

    // XCD batch-partition swizzle; block handles batches b0, b0+1 (same graph)
    const int L     = blockIdx.x;
    const int xcd   = L & (NXCD - 1);
    const int sl    = L >> 3;
    const int pair  = sl / NCHUNK;
    const int chunk = sl % NCHUNK;
    const int b0    = xcd * (BPB * PAIRS) + pair * BPB;
    const int n0    = chunk * TR;

    if (tid < 32) {
        int n = n0 + tid;
        int cr = (n < NN) ? cnt[n] : 0;
        sCnt[tid]  = min(cr, SL);
        sDinv[tid] = rsqrtf((float)(cr + 1));
    }
    if (tid < 128) { yred[0][tid] = 0.f; yred[1][tid] = 0.f; }
    __syncthreads();
    if (tid == 0) {
        int s = 0;
        for (int j = 0; j < 32; j++) { sBase[j] = s; s += sCnt[j]; }
        sBase[32] = s;
    }

    const int wv = tid >> 6, ln = tid & 63;

    // ---- per-row wsum from out-CSR: wsum = dinv*(dinv + sum rsqrt(cnt[dst]+1)) ----
    for (int ii = 0; ii < 8; ii++) {
        const int j = wv * 8 + ii;
        const int n = n0 + j;
        float part = 0.f;
        if (n < NN) {
            int oc = min(ocnt[n], SL);
            const int* op = &slot_out[(size_t)n * SL];
            for (int base = 0; base < oc; base += 64)
                if (base + ln < oc)
                    part += rsqrtf((float)(cnt[op[base + ln]] + 1));
        }
        #pragma unroll
        for (int off = 32; off; off >>= 1) part += __shfl_down(part, off, 64);
        if (ln == 0) {
            float d = sDinv[j];
            sWn[j] = (n < NN) ? d * (d + part) : 0.f;
        }
    }
    __syncthreads();
    const bool staged = (sBase[32] <= ECAP);

    // ---- stage in-edges; compute w at staging time ----
    if (staged) {
        for (int ii = 0; ii < 8; ii++) {
            int j = wv * 8 + ii;
            int c = sCnt[j];
            float dd = sDinv[j];
            const int* sp = &slot_in[(size_t)(n0 + j) * SL];
            for (int base = 0; base < c; base += 64) {
                if (base + ln < c) {
                    int sidx = sp[base + ln];
                    float w = rsqrtf((float)(cnt[sidx] + 1)) * dd;
                    sEdge[sBase[j] + base + ln] = make_int2(sidx, __float_as_int(w));
                }
            }
        }
    }
    __syncthreads();

    // ---- gather: wave owns row; lane ln owns features 2ln,2ln+1 (one u32/row) ----
    const uint* __restrict__ Xu0 = (const uint*)(xbf + (size_t)b0 * NN * ND);
    const uint* __restrict__ Xu1 = (const uint*)(xbf + (size_t)(b0 + 1) * NN * ND);
    #pragma unroll 1
    for (int ii = 0; ii < 8; ii++) {
        const int j = wv * 8 + ii;
        const int n = n0 + j;
        float2 a0 = make_float2(0.f, 0.f), a1 = a0, a0b = a0, a1b = a0;
        if (n < NN) {
            float sn = sDinv[j]; sn *= sn;
            uint u0 = Xu0[n * 64 + ln], u1 = Xu1[n * 64 + ln];
            a0.x = sn * __uint_as_float(u0 << 16);
            a0.y = sn * __uint_as_float(u0 & 0xffff0000u);
            a1.x = sn * __uint_as_float(u1 << 16);
            a1.y = sn * __uint_as_float(u1 & 0xffff0000u);
            const int c = sCnt[j];
            if (staged) {
                const int e0 = sBase[j], e1 = e0 + c;
                int e = e0;
                for (; e + 8 <= e1; e += 8) {
                    int sidx[8]; float w[8]; uint q0[8], q1[8];
                    #pragma unroll
                    for (int q = 0; q < 8; q++) {
                        int2 ed = sEdge[e + q];
                        sidx[q] = ed.x; w[q] = __int_as_float(ed.y);
                    }
                    #pragma unroll
                    for (int q = 0; q < 8; q++) {     // 16 independent 256B loads
                        q0[q] = Xu0[sidx[q] * 64 + ln];
                        q1[q] = Xu1[sidx[q] * 64 + ln];
                    }
                    #pragma unroll
                    for (int q = 0; q < 8; q++) {     // dual accumulators
                        float x0l = __uint_as_float(q0[q] << 16);
                        float x0h = __uint_as_float(q0[q] & 0xffff0000u);
                        float x1l = __uint_as_float(q1[q] << 16);
                        float x1h = __uint_as_float(q1[q] & 0xffff0000u);
                        if (q & 1) {
                            a0b.x = fmaf(w[q], x0l, a0b.x);
                            a0b.y = fmaf(w[q], x0h, a0b.y);
                            a1b.x = fmaf(w[q], x1l, a1b.x);
                            a1b.y = fmaf(w[q], x1h, a1b.y);
                        } else {
                            a0.x = fmaf(w[q], x0l, a0.x);
                            a0.y = fmaf(w[q], x0h, a0.y);
                            a1.x = fmaf(w[q], x1l, a1.x);
                            a1.y = fmaf(w[q], x1h, a1.y);
                        }
                    }
                }
                for (; e < e1; e++) {
                    int2 ed = sEdge[e];
                    float w = __int_as_float(ed.y);
                    uint u0e = Xu0[ed.x * 64 + ln], u1e = Xu1[ed.x * 64 + ln];
                    a0.x = fmaf(w, __uint_as_float(u0e << 16), a0.x);
                    a0.y = fmaf(w, __uint_as_float(u0e & 0xffff0000u), a0.y);
                    a1.x = fmaf(w, __uint_as_float(u1e << 16), a1.x);
                    a1.y = fmaf(w, __uint_as_float(u1e & 0xffff0000u), a1.y);
                }
            } else {
                // astronomically-rare fallback: read slots directly
                const int* sp = &slot_in[(size_t)n * SL];
                float dd = sDinv[j];
                for (int e = 0; e < c; e++) {
                    int sidx = sp[e];
                    float w = rsqrtf((float)(cnt[sidx] + 1)) * dd;
                    uint u0e = Xu0[sidx * 64 + ln], u1e = Xu1[sidx * 64 + ln];
                    a0.x = fmaf(w, __uint_as_float(u0e << 16), a0.x);
                    a0.y = fmaf(w, __uint_as_float(u0e & 0xffff0000u), a0.y);
                    a1.x = fmaf(w, __uint_as_float(u1e << 16), a1.x);
                    a1.y = fmaf(w, __uint_as_float(u1e & 0xffff0000u), a1.y);
                }
            }
            a0.x += a0b.x; a0.y += a0b.y;
            a1.x += a1b.x; a1.y += a1b.y;
        }
        AsU[0][j * 68 + ln] = pack_bf16x2(a0.x, a0.y);
        AsU[1][j * 68 + ln] = pack_bf16x2(a1.x, a1.y);
    }
    __syncthreads();

    // ---- MFMA GEMM: wave wv owns n-tiles {2wv, 2wv+1}; 32 mfma per wave ----
    const int lane15 = ln & 15, quad = ln >> 4;
    f32x4 zero4 = {0.f, 0.f, 0.f, 0.f};
    f32x4 acc[2][2][2];                  // [batch][mt][nt2]
    #pragma unroll
    for (int b = 0; b < 2; b++)
        #pragma unroll
        for (int mt = 0; mt < 2; mt++)
            #pragma unroll
            for (int nt2 = 0; nt2 < 2; nt2++) acc[b][mt][nt2] = zero4;

    bf16x8 wfr[2][4];
    const bf16x8* Wf8 = (const bf16x8*)wfrag;
    #pragma unroll
    for (int nt2 = 0; nt2 < 2; nt2++)
        #pragma unroll
        for (int kc = 0; kc < 4; kc++)
            wfr[nt2][kc] = Wf8[(((2 * wv + nt2) * 4 + kc) * 64) + ln];

    const bf16x8* A8_0 = (const bf16x8*)AsU[0];   // row stride 17 frags
    const bf16x8* A8_1 = (const bf16x8*)AsU[1];
    #pragma unroll
    for (int mt = 0; mt < 2; mt++) {
        const int r = mt * 16 + lane15;
        #pragma unroll
        for (int kc = 0; kc < 4; kc++) {
            bf16x8 af0 = A8_0[r * 17 + kc * 4 + quad];
            bf16x8 af1 = A8_1[r * 17 + kc * 4 + quad];
            #pragma unroll
            for (int nt2 = 0; nt2 < 2; nt2++) {
                acc[0][mt][nt2] = __builtin_amdgcn_mfma_f32_16x16x32_bf16(
                    af0, wfr[nt2][kc], acc[0][mt][nt2], 0, 0, 0);
                acc[1][mt][nt2] = __builtin_amdgcn_mfma_f32_16x16x32_bf16(
                    af1, wfr[nt2][kc], acc[1][mt][nt2], 0, 0, 0);
            }
        }
    }

    // ---- epilogue: relu + wsum-weighted reduce (C-layout aware) ----
    #pragma unroll
    for (int nt2 = 0; nt2 < 2; nt2++) {
        int cg = (2 * wv + nt2) * 16 + lane15;
        float bias = b1[cg];
        #pragma unroll
        for (int b = 0; b < 2; b++) {
            float part = 0.f;
            #pragma unroll
            for (int mt = 0; mt < 2; mt++) {
                f32x4 a = acc[b][mt][nt2];
                #pragma unroll
                for (int r = 0; r < 4; r++) {
                    int m = mt * 16 + quad * 4 + r;
                    part = fmaf(sWn[m], fmaxf(a[r] + bias, 0.f), part);
                }
            }
            atomicAdd(&yred[b][cg], part);
        }
    }
    __syncthreads();
    if (tid < 128)
        ypart[((size_t)b0 * NCHUNK + chunk) * ND + tid] = yred[0][tid];
    else
        ypart[((size_t)(b0 + 1) * NCHUNK + chunk) * ND + (tid - 128)] = yred[1][tid - 128];
}

// ---- N4: out[b,:] = (1/N) * (sum_chunk ypart[b,chunk,:]) @ W2 + b2 ----
__global__ __launch_bounds__(128) void k_out(const float* __restrict__ ypart,
                                             const float* __restrict__ W2,
                                             const float* __restrict__ b2,
                                             float* __restrict__ out) {
    __shared__ float ys[128];
    const int b = blockIdx.x;
    const int d = threadIdx.x;
    float s = 0.f;
    for (int c = 0; c < NCHUNK; c++)
        s += ypart[((size_t)b * NCHUNK + c) * ND + d];
    ys[d] = s * (1.f / (float)NN);
    __syncthreads();
    float acc = b2[d];
    #pragma unroll 8
    for (int k = 0; k < 128; k++)
        acc = fmaf(ys[k], W2[k * ND + d], acc);
    out[b * ND + d] = acc;
}

extern "C" void kernel_launch(void* const* d_in, const int* in_sizes, int n_in,
                              void* d_out, int out_size, void* d_ws, size_t ws_size,
                              hipStream_t stream) {
    (void)in_sizes; (void)n_in; (void)out_size; (void)ws_size;
    const float* X   = (const float*)d_in[0];
    const int*   src = (const int*)d_in[1];
    const int*   dst = (const int*)d_in[2];
    const float* W1  = (const float*)d_in[3];
    const float* b1  = (const float*)d_in[4];
    const float* W2  = (const float*)d_in[5];
    const float* b2  = (const float*)d_in[6];
    float* out = (float*)d_out;

    char* ws = (char*)d_ws;
    int*    cnt   = (int*)   (ws + OFF_CNT);
    int*    ocnt  = (int*)   (ws + OFF_OCNT);
    int*    sli   = (int*)   (ws + OFF_SLI);
    int*    slo   = (int*)   (ws + OFF_SLO);
    uint*   wfb   = (uint*)  (ws + OFF_WF);
    ushort* xbf   = (ushort*)(ws + OFF_XBF);
    float*  ypart = (float*) (ws + OFF_YP);

    (void)hipMemsetAsync(ws, 0, MEMSET_BYTES, stream);            // cnt + ocnt
    k_fill<<<FILL_GRID, 256, 0, stream>>>(X, xbf, W1, wfb, src, dst,
                                          cnt, ocnt, sli, slo);
    k_fused<<<GRID_FUSED, 256, 0, stream>>>(xbf, cnt, ocnt, sli, slo, wfb, b1, ypart);
    k_out<<<NB, 128, 0, stream>>>(ypart, W2, b2, out);
}